// Round 17
// baseline (445.763 us; speedup 1.0000x reference)
//
#include <hip/hip_runtime.h>
#include <math.h>

#define NB 32
#define NN 4096
#define DK 256
#define DV 256
#define ROWS 32

typedef float f32x2 __attribute__((ext_vector_type(2)));

// packed fp32 FMA: two independent IEEE f32 FMAs (bit-identical to v_fma_f32)
__device__ __forceinline__ void pkfma(f32x2 &acc, f32x2 a, f32x2 b) {
  asm("v_pk_fma_f32 %0, %1, %2, %0" : "+v"(acc) : "v"(a), "v"(b));
}

// ---- branch-free double exp, f32-CR (frozen contract, proven R9-R15) ----
__device__ __forceinline__ float fexp_cr(float xf) {
  const double INV_LN2 = 1.4426950408889634;
  const double LN2_HI = 6.93147180369123816490e-01;
  const double LN2_LO = 1.90821492927058770002e-10;
  double xd = (double)xf;
  double qd = floor(fma(xd, INV_LN2, 0.5));
  double r = fma(qd, -LN2_HI, xd);
  r = fma(qd, -LN2_LO, r);
  double p = 2.755731922398589e-7;
  p = fma(p, r, 2.7557319223985893e-6);
  p = fma(p, r, 2.48015873015873e-5);
  p = fma(p, r, 1.984126984126984e-4);
  p = fma(p, r, 1.3888888888888889e-3);
  p = fma(p, r, 8.333333333333333e-3);
  p = fma(p, r, 4.1666666666666664e-2);
  p = fma(p, r, 1.6666666666666666e-1);
  p = fma(p, r, 5.0e-1);
  p = fma(p, r, 1.0);
  p = fma(p, r, 1.0);
  long long sb = ((long long)(1023 + (int)qd)) << 52;
  double s = __longlong_as_double(sb);
  return (float)(p * s);
}

// ---- K1: H prep, full-chip parallel (grid NB x 8, 32 cols/block).
// Frozen bit-path: per-column STRICT SEQUENTIAL norm chain over d.
__global__ __launch_bounds__(256) void k_hprep(const float* __restrict__ H,
    float* __restrict__ Hn, float* __restrict__ HT) {
  const int b = blockIdx.x;
  const int k0 = blockIdx.y * 32;
  const int t = threadIdx.x;
  const int c = t & 31, g = t >> 5;
  const float* __restrict__ Hb = H + (size_t)b * DK * DV;

  __shared__ float nr[32];
  if (t < 32) {
    float ss = 0.0f;
    for (int d = 0; d < DK; ++d) {
      float h = Hb[d * DV + k0 + t];
      ss = __fadd_rn(ss, __fmul_rn(h, h));
    }
    nr[t] = fmaxf(__fsqrt_rn(ss), 1e-8f);
  }
  __syncthreads();

  for (int d0 = 0; d0 < DK; d0 += 8) {
    const int d = d0 + g;
    float h = Hb[d * DV + k0 + c];
    Hn[(size_t)b * DK * DV + (size_t)d * DV + k0 + c] = __fdiv_rn(h, nr[c]);
  }

  __shared__ float tile[32][33];
  for (int d0 = 0; d0 < DK; d0 += 32) {
    __syncthreads();
#pragma unroll
    for (int j = 0; j < 4; ++j) {
      int dl = g + 8 * j;
      tile[dl][c] = Hb[(size_t)(d0 + dl) * DV + k0 + c];
    }
    __syncthreads();
#pragma unroll
    for (int j = 0; j < 4; ++j) {
      int kl = g + 8 * j;
      HT[(size_t)b * DV * DK + (size_t)(k0 + kl) * DK + d0 + c] = tile[c][kl];
    }
  }
}

// ---- K2: 32 rows/block; csT[d][36] + pk_fma GEMM; selection 2-row interleaved.
// All frozen bit-paths identical to R15 (the 435us PASS kernel).
__global__ __launch_bounds__(256) void k_main(
    const float* __restrict__ C, const float* __restrict__ Hn,
    const float* __restrict__ HT, const float* __restrict__ temp,
    float* __restrict__ out) {
  const int b = blockIdx.x >> 7;
  const int n0 = (blockIdx.x & 127) * ROWS;
  const int t = threadIdx.x;
  const int w = t >> 6, l = t & 63;

  __shared__ float smem[DK * 36];      // csT[d][36]; xs[32][258] overlays after GEMM
  __shared__ float nrm32[ROWS];
  __shared__ float m32[ROWS];
  __shared__ float zrow[ROWS];
#define CST(d, r) smem[(d) * 36 + (r)]
#define XS(r, k)  smem[(r) * 258 + (k)]

  // staging: float4 global reads (pure data movement, no numeric contract)
  const float* __restrict__ Cb = C + ((size_t)b * NN + n0) * DK;
  for (int i4 = t; i4 < (ROWS * DK) / 4; i4 += 256) {
    const int i = i4 * 4;
    const int r = i >> 8, d = i & 255;
    const float4 v = *reinterpret_cast<const float4*>(Cb + i);
    CST(d + 0, r) = v.x;
    CST(d + 1, r) = v.y;
    CST(d + 2, r) = v.z;
    CST(d + 3, r) = v.w;
  }
  __syncthreads();

  // C row norms: STRICT SEQUENTIAL 256-chain (frozen), 32 rows in parallel
  if (t < ROWS) {
    float ss = 0.0f;
    for (int d = 0; d < DK; ++d) {
      float c = CST(d, t);
      ss = __fadd_rn(ss, __fmul_rn(c, c));
    }
    nrm32[t] = fmaxf(__fsqrt_rn(ss), 1e-8f);
  }
  __syncthreads();
  for (int i = t; i < ROWS * DK; i += 256) {
    const int d = i & 255, r = i >> 8;
    CST(d, r) = __fdiv_rn(CST(d, r), nrm32[r]);
  }
  __syncthreads();

  const float tt = fmaxf(temp[0], 0.1f);
  const float tp = __fadd_rn(tt, 1e-8f);

  // sims GEMM: thread = 2 cols x 16 rows (8 row-pairs), pk_fma, ascending-d
  const int rbase = (t >> 7) * 16;
  const int c0 = t & 127;
  const int c1 = c0 + 128;
  f32x2 acc0[8], acc1[8];
#pragma unroll
  for (int j = 0; j < 8; ++j) {
    acc0[j] = (f32x2)(0.0f, 0.0f);
    acc1[j] = (f32x2)(0.0f, 0.0f);
  }
  const float* __restrict__ Hnb = Hn + (size_t)b * DK * DV;
  for (int d0 = 0; d0 < DK; d0 += 4) {
#pragma unroll
    for (int dd = 0; dd < 4; ++dd) {
      const int d = d0 + dd;
      const float ha = Hnb[(size_t)d * DV + c0];
      const float hb = Hnb[(size_t)d * DV + c1];
      f32x2 hha; hha.x = ha; hha.y = ha;
      f32x2 hhb; hhb.x = hb; hhb.y = hb;
#pragma unroll
      for (int j4 = 0; j4 < 4; ++j4) {
        const float4 cq = *reinterpret_cast<const float4*>(&CST(d, rbase + 4 * j4));
        f32x2 lo; lo.x = cq.x; lo.y = cq.y;
        f32x2 hi; hi.x = cq.z; hi.y = cq.w;
        pkfma(acc0[2 * j4],     lo, hha);
        pkfma(acc0[2 * j4 + 1], hi, hha);
        pkfma(acc1[2 * j4],     lo, hhb);
        pkfma(acc1[2 * j4 + 1], hi, hhb);
      }
    }
  }
  __syncthreads();   // all csT reads done before xs overlay writes

  // x = fl32(sims/tp) (frozen CR div), into overlaid xs
#pragma unroll
  for (int j = 0; j < 8; ++j) {
    XS(rbase + 2 * j,     c0) = __fdiv_rn(acc0[j].x, tp);
    XS(rbase + 2 * j + 1, c0) = __fdiv_rn(acc0[j].y, tp);
    XS(rbase + 2 * j,     c1) = __fdiv_rn(acc1[j].x, tp);
    XS(rbase + 2 * j + 1, c1) = __fdiv_rn(acc1[j].y, tp);
  }
  __syncthreads();

  // row max (exact): 8 threads per row
  {
    const int r = t >> 3, j0 = t & 7;
    float m = XS(r, j0);
#pragma unroll
    for (int i = 1; i < 32; ++i) m = fmaxf(m, XS(r, j0 + 8 * i));
    m = fmaxf(m, __shfl_xor(m, 1, 64));
    m = fmaxf(m, __shfl_xor(m, 2, 64));
    m = fmaxf(m, __shfl_xor(m, 4, 64));
    if (j0 == 0) m32[r] = m;
  }
  __syncthreads();

  // e = CR exp(x - m) in place (frozen)
  for (int r = 0; r < ROWS; ++r)
    XS(r, t) = fexp_cr(__fsub_rn(XS(r, t), m32[r]));
  __syncthreads();

  // Z: STRICT SEQUENTIAL 256-chain per row (frozen)
  if (t < ROWS) {
    float zacc = 0.0f;
    for (int k = 0; k < DV; ++k) zacc = __fadd_rn(zacc, XS(t, k));
    zrow[t] = zacc;
  }
  __syncthreads();

  // selection + output: 2 rows interleaved (independent chains -> DS-latency ILP)
  for (int p = 0; p < 4; ++p) {
    const int ra = w * 8 + 2 * p;
    const int rb = ra + 1;
    const float Za = zrow[ra];
    const float Zb = zrow[rb];
    unsigned int a0 = __float_as_uint(__fdiv_rn(XS(ra, l), Za));
    unsigned int a1 = __float_as_uint(__fdiv_rn(XS(ra, l + 64), Za));
    unsigned int a2 = __float_as_uint(__fdiv_rn(XS(ra, l + 128), Za));
    unsigned int a3 = __float_as_uint(__fdiv_rn(XS(ra, l + 192), Za));
    unsigned int b0 = __float_as_uint(__fdiv_rn(XS(rb, l), Zb));
    unsigned int b1 = __float_as_uint(__fdiv_rn(XS(rb, l + 64), Zb));
    unsigned int b2 = __float_as_uint(__fdiv_rn(XS(rb, l + 128), Zb));
    unsigned int b3 = __float_as_uint(__fdiv_rn(XS(rb, l + 192), Zb));

    float avalA[16], avalB[16];
    int idxA[16], idxB[16];
#pragma unroll
    for (int e = 0; e < 16; ++e) {
      unsigned int la = a0 > a1 ? a0 : a1;
      unsigned int l2a = a2 > a3 ? a2 : a3;
      la = la > l2a ? la : l2a;
      unsigned int lb = b0 > b1 ? b0 : b1;
      unsigned int l2b = b2 > b3 ? b2 : b3;
      lb = lb > l2b ? lb : l2b;
#pragma unroll
      for (int s = 1; s < 64; s <<= 1) {
        unsigned int oa = __shfl_xor(la, s, 64);
        unsigned int ob = __shfl_xor(lb, s, 64);
        la = oa > la ? oa : la;
        lb = ob > lb ? ob : lb;
      }
      unsigned long long ba0 = __ballot(a0 == la);
      unsigned long long ba1 = __ballot(a1 == la);
      unsigned long long ba2 = __ballot(a2 == la);
      unsigned long long ba3 = __ballot(a3 == la);
      unsigned long long bb0 = __ballot(b0 == lb);
      unsigned long long bb1 = __ballot(b1 == lb);
      unsigned long long bb2 = __ballot(b2 == lb);
      unsigned long long bb3 = __ballot(b3 == lb);
      int ida, idb;
      if (ba0)      ida = __ffsll(ba0) - 1;
      else if (ba1) ida = 64 + __ffsll(ba1) - 1;
      else if (ba2) ida = 128 + __ffsll(ba2) - 1;
      else          ida = 192 + __ffsll(ba3) - 1;
      if (bb0)      idb = __ffsll(bb0) - 1;
      else if (bb1) idb = 64 + __ffsll(bb1) - 1;
      else if (bb2) idb = 128 + __ffsll(bb2) - 1;
      else          idb = 192 + __ffsll(bb3) - 1;
      avalA[e] = __uint_as_float(la);
      avalB[e] = __uint_as_float(lb);
      idxA[e] = ida;
      idxB[e] = idb;
      if (l == (ida & 63)) {
        const int slot = ida >> 6;
        if (slot == 0) a0 = 0u;
        else if (slot == 1) a1 = 0u;
        else if (slot == 2) a2 = 0u;
        else a3 = 0u;
      }
      if (l == (idb & 63)) {
        const int slot = idb >> 6;
        if (slot == 0) b0 = 0u;
        else if (slot == 1) b1 = 0u;
        else if (slot == 2) b2 = 0u;
        else b3 = 0u;
      }
    }

    float Sa = avalA[0], Sb = avalB[0];
#pragma unroll
    for (int e = 1; e < 16; ++e) {
      Sa = __fadd_rn(Sa, avalA[e]);
      Sb = __fadd_rn(Sb, avalB[e]);
    }
    const float rSa = __frcp_rn(__fadd_rn(Sa, 1e-8f));
    const float rSb = __frcp_rn(__fadd_rn(Sb, 1e-8f));

    float oa0 = 0.f, oa1 = 0.f, oa2 = 0.f, oa3 = 0.f;
    float ob0 = 0.f, ob1 = 0.f, ob2 = 0.f, ob3 = 0.f;
    const float* __restrict__ HTb = HT + (size_t)b * DV * DK;
#pragma unroll
    for (int e = 0; e < 16; ++e) {
      const float wja = avalA[e] * rSa;
      const float wjb = avalB[e] * rSb;
      const float* __restrict__ hra = HTb + (size_t)idxA[e] * DK;
      const float* __restrict__ hrb = HTb + (size_t)idxB[e] * DK;
      oa0 = fmaf(wja, hra[l], oa0);
      ob0 = fmaf(wjb, hrb[l], ob0);
      oa1 = fmaf(wja, hra[l + 64], oa1);
      ob1 = fmaf(wjb, hrb[l + 64], ob1);
      oa2 = fmaf(wja, hra[l + 128], oa2);
      ob2 = fmaf(wjb, hrb[l + 128], ob2);
      oa3 = fmaf(wja, hra[l + 192], oa3);
      ob3 = fmaf(wjb, hrb[l + 192], ob3);
    }
    float* __restrict__ orowa = out + ((size_t)(b * NN + n0 + ra)) * DK;
    float* __restrict__ orowb = out + ((size_t)(b * NN + n0 + rb)) * DK;
    orowa[l] = oa0;
    orowa[l + 64] = oa1;
    orowa[l + 128] = oa2;
    orowa[l + 192] = oa3;
    orowb[l] = ob0;
    orowb[l + 64] = ob1;
    orowb[l + 128] = ob2;
    orowb[l + 192] = ob3;
  }
#undef CST
#undef XS
}

extern "C" void kernel_launch(void* const* d_in, const int* in_sizes, int n_in,
                              void* d_out, int out_size, void* d_ws, size_t ws_size,
                              hipStream_t stream) {
  const float* C = (const float*)d_in[0];
  const float* H = (const float*)d_in[1];
  const float* temp = (const float*)d_in[2];
  float* out = (float*)d_out;
  char* ws = (char*)d_ws;

  float* Hn = (float*)ws;                 // 8 MiB
  float* HT = (float*)(ws + 8388608);     // 8 MiB

  hipLaunchKernelGGL(k_hprep, dim3(NB, 8), dim3(256), 0, stream, H, Hn, HT);
  hipLaunchKernelGGL(k_main, dim3(NB * (NN / ROWS)), dim3(256), 0, stream,
                     C, Hn, HT, temp, out);
}

// Round 18
// 430.504 us; speedup vs baseline: 1.0354x; 1.0354x over previous
//
#include <hip/hip_runtime.h>
#include <math.h>

#define NB 32
#define NN 4096
#define DK 256
#define DV 256
#define ROWS 32

typedef float f32x2 __attribute__((ext_vector_type(2)));

// packed fp32 FMA: two independent IEEE f32 FMAs (bit-identical to v_fma_f32)
__device__ __forceinline__ void pkfma(f32x2 &acc, f32x2 a, f32x2 b) {
  asm("v_pk_fma_f32 %0, %1, %2, %0" : "+v"(acc) : "v"(a), "v"(b));
}

// ---- branch-free double exp, f32-CR (frozen contract, proven R9-R17) ----
__device__ __forceinline__ float fexp_cr(float xf) {
  const double INV_LN2 = 1.4426950408889634;
  const double LN2_HI = 6.93147180369123816490e-01;
  const double LN2_LO = 1.90821492927058770002e-10;
  double xd = (double)xf;
  double qd = floor(fma(xd, INV_LN2, 0.5));
  double r = fma(qd, -LN2_HI, xd);
  r = fma(qd, -LN2_LO, r);
  double p = 2.755731922398589e-7;
  p = fma(p, r, 2.7557319223985893e-6);
  p = fma(p, r, 2.48015873015873e-5);
  p = fma(p, r, 1.984126984126984e-4);
  p = fma(p, r, 1.3888888888888889e-3);
  p = fma(p, r, 8.333333333333333e-3);
  p = fma(p, r, 4.1666666666666664e-2);
  p = fma(p, r, 1.6666666666666666e-1);
  p = fma(p, r, 5.0e-1);
  p = fma(p, r, 1.0);
  p = fma(p, r, 1.0);
  long long sb = ((long long)(1023 + (int)qd)) << 52;
  double s = __longlong_as_double(sb);
  return (float)(p * s);
}

// ---- K1: H prep, full-chip parallel (grid NB x 8, 32 cols/block).
// Frozen bit-path: per-column STRICT SEQUENTIAL norm chain over d.
__global__ __launch_bounds__(256) void k_hprep(const float* __restrict__ H,
    float* __restrict__ Hn, float* __restrict__ HT) {
  const int b = blockIdx.x;
  const int k0 = blockIdx.y * 32;
  const int t = threadIdx.x;
  const int c = t & 31, g = t >> 5;
  const float* __restrict__ Hb = H + (size_t)b * DK * DV;

  __shared__ float nr[32];
  if (t < 32) {
    float ss = 0.0f;
    for (int d = 0; d < DK; ++d) {
      float h = Hb[d * DV + k0 + t];
      ss = __fadd_rn(ss, __fmul_rn(h, h));
    }
    nr[t] = fmaxf(__fsqrt_rn(ss), 1e-8f);
  }
  __syncthreads();

  for (int d0 = 0; d0 < DK; d0 += 8) {
    const int d = d0 + g;
    float h = Hb[d * DV + k0 + c];
    Hn[(size_t)b * DK * DV + (size_t)d * DV + k0 + c] = __fdiv_rn(h, nr[c]);
  }

  __shared__ float tile[32][33];
  for (int d0 = 0; d0 < DK; d0 += 32) {
    __syncthreads();
#pragma unroll
    for (int j = 0; j < 4; ++j) {
      int dl = g + 8 * j;
      tile[dl][c] = Hb[(size_t)(d0 + dl) * DV + k0 + c];
    }
    __syncthreads();
#pragma unroll
    for (int j = 0; j < 4; ++j) {
      int kl = g + 8 * j;
      HT[(size_t)b * DV * DK + (size_t)(k0 + kl) * DK + d0 + c] = tile[c][kl];
    }
  }
}

// ---- K2: 32 rows/block; csT[d][36] + pk_fma GEMM; selection 2-row interleaved.
// R15 base (435us PASS) + bank-conflict-free staging/div lane mapping.
__global__ __launch_bounds__(256) void k_main(
    const float* __restrict__ C, const float* __restrict__ Hn,
    const float* __restrict__ HT, const float* __restrict__ temp,
    float* __restrict__ out) {
  const int b = blockIdx.x >> 7;
  const int n0 = (blockIdx.x & 127) * ROWS;
  const int t = threadIdx.x;
  const int w = t >> 6, l = t & 63;

  __shared__ float smem[DK * 36];      // csT[d][36]; xs[32][258] overlays after GEMM
  __shared__ float nrm32[ROWS];
  __shared__ float m32[ROWS];
  __shared__ float zrow[ROWS];
#define CST(d, r) smem[(d) * 36 + (r)]
#define XS(r, k)  smem[(r) * 258 + (k)]

  // conflict-free staging mapping: bank = 4*(t&7) + ((t>>3)&3) + const -> all 32
  // banks per 32-lane group (2 lanes/bank for wave64 = free). Globals: 4x32B
  // segments per group, same-wave sector halves merge in the coalescer.
  const int dl3 = t & 7, rl2 = (t >> 3) & 3, dm3 = t >> 5;
  const float* __restrict__ Cb = C + ((size_t)b * NN + n0) * DK;
#pragma unroll
  for (int j = 0; j < 32; ++j) {
    const int d = dl3 + 8 * dm3 + 64 * (j & 3);
    const int r = rl2 + 4 * (j >> 2);
    CST(d, r) = Cb[r * 256 + d];
  }
  __syncthreads();

  // C row norms: STRICT SEQUENTIAL 256-chain (frozen), 32 rows in parallel
  if (t < ROWS) {
    float ss = 0.0f;
    for (int d = 0; d < DK; ++d) {
      float c = CST(d, t);
      ss = __fadd_rn(ss, __fmul_rn(c, c));
    }
    nrm32[t] = fmaxf(__fsqrt_rn(ss), 1e-8f);
  }
  __syncthreads();
  // divide phase: same conflict-free mapping (element-independent ops)
#pragma unroll
  for (int j = 0; j < 32; ++j) {
    const int d = dl3 + 8 * dm3 + 64 * (j & 3);
    const int r = rl2 + 4 * (j >> 2);
    CST(d, r) = __fdiv_rn(CST(d, r), nrm32[r]);
  }
  __syncthreads();

  const float tt = fmaxf(temp[0], 0.1f);
  const float tp = __fadd_rn(tt, 1e-8f);

  // sims GEMM: thread = 2 cols x 16 rows (8 row-pairs), pk_fma, ascending-d
  const int rbase = (t >> 7) * 16;
  const int c0 = t & 127;
  const int c1 = c0 + 128;
  f32x2 acc0[8], acc1[8];
#pragma unroll
  for (int j = 0; j < 8; ++j) {
    acc0[j] = (f32x2)(0.0f, 0.0f);
    acc1[j] = (f32x2)(0.0f, 0.0f);
  }
  const float* __restrict__ Hnb = Hn + (size_t)b * DK * DV;
  for (int d0 = 0; d0 < DK; d0 += 4) {
#pragma unroll
    for (int dd = 0; dd < 4; ++dd) {
      const int d = d0 + dd;
      const float ha = Hnb[(size_t)d * DV + c0];
      const float hb = Hnb[(size_t)d * DV + c1];
      f32x2 hha; hha.x = ha; hha.y = ha;
      f32x2 hhb; hhb.x = hb; hhb.y = hb;
#pragma unroll
      for (int j4 = 0; j4 < 4; ++j4) {
        const float4 cq = *reinterpret_cast<const float4*>(&CST(d, rbase + 4 * j4));
        f32x2 lo; lo.x = cq.x; lo.y = cq.y;
        f32x2 hi; hi.x = cq.z; hi.y = cq.w;
        pkfma(acc0[2 * j4],     lo, hha);
        pkfma(acc0[2 * j4 + 1], hi, hha);
        pkfma(acc1[2 * j4],     lo, hhb);
        pkfma(acc1[2 * j4 + 1], hi, hhb);
      }
    }
  }
  __syncthreads();   // all csT reads done before xs overlay writes

  // x = fl32(sims/tp) (frozen CR div), into overlaid xs
#pragma unroll
  for (int j = 0; j < 8; ++j) {
    XS(rbase + 2 * j,     c0) = __fdiv_rn(acc0[j].x, tp);
    XS(rbase + 2 * j + 1, c0) = __fdiv_rn(acc0[j].y, tp);
    XS(rbase + 2 * j,     c1) = __fdiv_rn(acc1[j].x, tp);
    XS(rbase + 2 * j + 1, c1) = __fdiv_rn(acc1[j].y, tp);
  }
  __syncthreads();

  // row max (exact): 8 threads per row
  {
    const int r = t >> 3, j0 = t & 7;
    float m = XS(r, j0);
#pragma unroll
    for (int i = 1; i < 32; ++i) m = fmaxf(m, XS(r, j0 + 8 * i));
    m = fmaxf(m, __shfl_xor(m, 1, 64));
    m = fmaxf(m, __shfl_xor(m, 2, 64));
    m = fmaxf(m, __shfl_xor(m, 4, 64));
    if (j0 == 0) m32[r] = m;
  }
  __syncthreads();

  // e = CR exp(x - m) in place (frozen)
  for (int r = 0; r < ROWS; ++r)
    XS(r, t) = fexp_cr(__fsub_rn(XS(r, t), m32[r]));
  __syncthreads();

  // Z: STRICT SEQUENTIAL 256-chain per row (frozen)
  if (t < ROWS) {
    float zacc = 0.0f;
    for (int k = 0; k < DV; ++k) zacc = __fadd_rn(zacc, XS(t, k));
    zrow[t] = zacc;
  }
  __syncthreads();

  // selection + output: 2 rows interleaved (independent chains -> DS-latency ILP)
  for (int p = 0; p < 4; ++p) {
    const int ra = w * 8 + 2 * p;
    const int rb = ra + 1;
    const float Za = zrow[ra];
    const float Zb = zrow[rb];
    unsigned int a0 = __float_as_uint(__fdiv_rn(XS(ra, l), Za));
    unsigned int a1 = __float_as_uint(__fdiv_rn(XS(ra, l + 64), Za));
    unsigned int a2 = __float_as_uint(__fdiv_rn(XS(ra, l + 128), Za));
    unsigned int a3 = __float_as_uint(__fdiv_rn(XS(ra, l + 192), Za));
    unsigned int b0 = __float_as_uint(__fdiv_rn(XS(rb, l), Zb));
    unsigned int b1 = __float_as_uint(__fdiv_rn(XS(rb, l + 64), Zb));
    unsigned int b2 = __float_as_uint(__fdiv_rn(XS(rb, l + 128), Zb));
    unsigned int b3 = __float_as_uint(__fdiv_rn(XS(rb, l + 192), Zb));

    float avalA[16], avalB[16];
    int idxA[16], idxB[16];
#pragma unroll
    for (int e = 0; e < 16; ++e) {
      unsigned int la = a0 > a1 ? a0 : a1;
      unsigned int l2a = a2 > a3 ? a2 : a3;
      la = la > l2a ? la : l2a;
      unsigned int lb = b0 > b1 ? b0 : b1;
      unsigned int l2b = b2 > b3 ? b2 : b3;
      lb = lb > l2b ? lb : l2b;
#pragma unroll
      for (int s = 1; s < 64; s <<= 1) {
        unsigned int oa = __shfl_xor(la, s, 64);
        unsigned int ob = __shfl_xor(lb, s, 64);
        la = oa > la ? oa : la;
        lb = ob > lb ? ob : lb;
      }
      unsigned long long ba0 = __ballot(a0 == la);
      unsigned long long ba1 = __ballot(a1 == la);
      unsigned long long ba2 = __ballot(a2 == la);
      unsigned long long ba3 = __ballot(a3 == la);
      unsigned long long bb0 = __ballot(b0 == lb);
      unsigned long long bb1 = __ballot(b1 == lb);
      unsigned long long bb2 = __ballot(b2 == lb);
      unsigned long long bb3 = __ballot(b3 == lb);
      int ida, idb;
      if (ba0)      ida = __ffsll(ba0) - 1;
      else if (ba1) ida = 64 + __ffsll(ba1) - 1;
      else if (ba2) ida = 128 + __ffsll(ba2) - 1;
      else          ida = 192 + __ffsll(ba3) - 1;
      if (bb0)      idb = __ffsll(bb0) - 1;
      else if (bb1) idb = 64 + __ffsll(bb1) - 1;
      else if (bb2) idb = 128 + __ffsll(bb2) - 1;
      else          idb = 192 + __ffsll(bb3) - 1;
      avalA[e] = __uint_as_float(la);
      avalB[e] = __uint_as_float(lb);
      idxA[e] = ida;
      idxB[e] = idb;
      if (l == (ida & 63)) {
        const int slot = ida >> 6;
        if (slot == 0) a0 = 0u;
        else if (slot == 1) a1 = 0u;
        else if (slot == 2) a2 = 0u;
        else a3 = 0u;
      }
      if (l == (idb & 63)) {
        const int slot = idb >> 6;
        if (slot == 0) b0 = 0u;
        else if (slot == 1) b1 = 0u;
        else if (slot == 2) b2 = 0u;
        else b3 = 0u;
      }
    }

    float Sa = avalA[0], Sb = avalB[0];
#pragma unroll
    for (int e = 1; e < 16; ++e) {
      Sa = __fadd_rn(Sa, avalA[e]);
      Sb = __fadd_rn(Sb, avalB[e]);
    }
    const float rSa = __frcp_rn(__fadd_rn(Sa, 1e-8f));
    const float rSb = __frcp_rn(__fadd_rn(Sb, 1e-8f));

    float oa0 = 0.f, oa1 = 0.f, oa2 = 0.f, oa3 = 0.f;
    float ob0 = 0.f, ob1 = 0.f, ob2 = 0.f, ob3 = 0.f;
    const float* __restrict__ HTb = HT + (size_t)b * DV * DK;
#pragma unroll
    for (int e = 0; e < 16; ++e) {
      const float wja = avalA[e] * rSa;
      const float wjb = avalB[e] * rSb;
      const float* __restrict__ hra = HTb + (size_t)idxA[e] * DK;
      const float* __restrict__ hrb = HTb + (size_t)idxB[e] * DK;
      oa0 = fmaf(wja, hra[l], oa0);
      ob0 = fmaf(wjb, hrb[l], ob0);
      oa1 = fmaf(wja, hra[l + 64], oa1);
      ob1 = fmaf(wjb, hrb[l + 64], ob1);
      oa2 = fmaf(wja, hra[l + 128], oa2);
      ob2 = fmaf(wjb, hrb[l + 128], ob2);
      oa3 = fmaf(wja, hra[l + 192], oa3);
      ob3 = fmaf(wjb, hrb[l + 192], ob3);
    }
    float* __restrict__ orowa = out + ((size_t)(b * NN + n0 + ra)) * DK;
    float* __restrict__ orowb = out + ((size_t)(b * NN + n0 + rb)) * DK;
    orowa[l] = oa0;
    orowa[l + 64] = oa1;
    orowa[l + 128] = oa2;
    orowa[l + 192] = oa3;
    orowb[l] = ob0;
    orowb[l + 64] = ob1;
    orowb[l + 128] = ob2;
    orowb[l + 192] = ob3;
  }
#undef CST
#undef XS
}

extern "C" void kernel_launch(void* const* d_in, const int* in_sizes, int n_in,
                              void* d_out, int out_size, void* d_ws, size_t ws_size,
                              hipStream_t stream) {
  const float* C = (const float*)d_in[0];
  const float* H = (const float*)d_in[1];
  const float* temp = (const float*)d_in[2];
  float* out = (float*)d_out;
  char* ws = (char*)d_ws;

  float* Hn = (float*)ws;                 // 8 MiB
  float* HT = (float*)(ws + 8388608);     // 8 MiB

  hipLaunchKernelGGL(k_hprep, dim3(NB, 8), dim3(256), 0, stream, H, Hn, HT);
  hipLaunchKernelGGL(k_main, dim3(NB * (NN / ROWS)), dim3(256), 0, stream,
                     C, Hn, HT, temp, out);
}

// Round 19
// 394.925 us; speedup vs baseline: 1.1287x; 1.0901x over previous
//
#include <hip/hip_runtime.h>
#include <math.h>

#define NB 32
#define NN 4096
#define DK 256
#define DV 256
#define ROWS 32

typedef float f32x2 __attribute__((ext_vector_type(2)));

// packed fp32 FMA: two independent IEEE f32 FMAs (bit-identical to v_fma_f32)
__device__ __forceinline__ void pkfma(f32x2 &acc, f32x2 a, f32x2 b) {
  asm("v_pk_fma_f32 %0, %1, %2, %0" : "+v"(acc) : "v"(a), "v"(b));
}

// wave64 u32 max via DPP ladder (pure VALU, no DS pipe); result uniform.
// row_shr:1/2/4/8 -> lane{15,31,47,63} hold 16-lane row maxima;
// row_bcast15 merges row pairs; row_bcast31 merges halves; lane63 = global max.
// bound_ctrl=true: invalid sources read 0 (identity for unsigned max).
__device__ __forceinline__ unsigned int wave_max_u32(unsigned int v) {
  int x = (int)v, t;
  t = __builtin_amdgcn_update_dpp(0, x, 0x111, 0xF, 0xF, true);  // row_shr:1
  x = ((unsigned)x > (unsigned)t) ? x : t;
  t = __builtin_amdgcn_update_dpp(0, x, 0x112, 0xF, 0xF, true);  // row_shr:2
  x = ((unsigned)x > (unsigned)t) ? x : t;
  t = __builtin_amdgcn_update_dpp(0, x, 0x114, 0xF, 0xF, true);  // row_shr:4
  x = ((unsigned)x > (unsigned)t) ? x : t;
  t = __builtin_amdgcn_update_dpp(0, x, 0x118, 0xF, 0xF, true);  // row_shr:8
  x = ((unsigned)x > (unsigned)t) ? x : t;
  t = __builtin_amdgcn_update_dpp(0, x, 0x142, 0xF, 0xF, true);  // row_bcast15
  x = ((unsigned)x > (unsigned)t) ? x : t;
  t = __builtin_amdgcn_update_dpp(0, x, 0x143, 0xF, 0xF, true);  // row_bcast31
  x = ((unsigned)x > (unsigned)t) ? x : t;
  return (unsigned int)__builtin_amdgcn_readlane(x, 63);
}

// ---- branch-free double exp, f32-CR (frozen contract, proven R9-R18) ----
__device__ __forceinline__ float fexp_cr(float xf) {
  const double INV_LN2 = 1.4426950408889634;
  const double LN2_HI = 6.93147180369123816490e-01;
  const double LN2_LO = 1.90821492927058770002e-10;
  double xd = (double)xf;
  double qd = floor(fma(xd, INV_LN2, 0.5));
  double r = fma(qd, -LN2_HI, xd);
  r = fma(qd, -LN2_LO, r);
  double p = 2.755731922398589e-7;
  p = fma(p, r, 2.7557319223985893e-6);
  p = fma(p, r, 2.48015873015873e-5);
  p = fma(p, r, 1.984126984126984e-4);
  p = fma(p, r, 1.3888888888888889e-3);
  p = fma(p, r, 8.333333333333333e-3);
  p = fma(p, r, 4.1666666666666664e-2);
  p = fma(p, r, 1.6666666666666666e-1);
  p = fma(p, r, 5.0e-1);
  p = fma(p, r, 1.0);
  p = fma(p, r, 1.0);
  long long sb = ((long long)(1023 + (int)qd)) << 52;
  double s = __longlong_as_double(sb);
  return (float)(p * s);
}

// ---- K1: H prep, full-chip parallel (grid NB x 8, 32 cols/block).
// Frozen bit-path: per-column STRICT SEQUENTIAL norm chain over d.
__global__ __launch_bounds__(256) void k_hprep(const float* __restrict__ H,
    float* __restrict__ Hn, float* __restrict__ HT) {
  const int b = blockIdx.x;
  const int k0 = blockIdx.y * 32;
  const int t = threadIdx.x;
  const int c = t & 31, g = t >> 5;
  const float* __restrict__ Hb = H + (size_t)b * DK * DV;

  __shared__ float nr[32];
  if (t < 32) {
    float ss = 0.0f;
    for (int d = 0; d < DK; ++d) {
      float h = Hb[d * DV + k0 + t];
      ss = __fadd_rn(ss, __fmul_rn(h, h));
    }
    nr[t] = fmaxf(__fsqrt_rn(ss), 1e-8f);
  }
  __syncthreads();

  for (int d0 = 0; d0 < DK; d0 += 8) {
    const int d = d0 + g;
    float h = Hb[d * DV + k0 + c];
    Hn[(size_t)b * DK * DV + (size_t)d * DV + k0 + c] = __fdiv_rn(h, nr[c]);
  }

  __shared__ float tile[32][33];
  for (int d0 = 0; d0 < DK; d0 += 32) {
    __syncthreads();
#pragma unroll
    for (int j = 0; j < 4; ++j) {
      int dl = g + 8 * j;
      tile[dl][c] = Hb[(size_t)(d0 + dl) * DV + k0 + c];
    }
    __syncthreads();
#pragma unroll
    for (int j = 0; j < 4; ++j) {
      int kl = g + 8 * j;
      HT[(size_t)b * DV * DK + (size_t)(k0 + kl) * DK + d0 + c] = tile[c][kl];
    }
  }
}

// ---- K2: 32 rows/block; csT[d][36] + pk_fma GEMM; conflict-free staging;
// selection 2-row interleaved with DPP max ladder. Frozen bit-paths = R18.
__global__ __launch_bounds__(256) void k_main(
    const float* __restrict__ C, const float* __restrict__ Hn,
    const float* __restrict__ HT, const float* __restrict__ temp,
    float* __restrict__ out) {
  const int b = blockIdx.x >> 7;
  const int n0 = (blockIdx.x & 127) * ROWS;
  const int t = threadIdx.x;
  const int w = t >> 6, l = t & 63;

  __shared__ float smem[DK * 36];      // csT[d][36]; xs[32][258] overlays after GEMM
  __shared__ float nrm32[ROWS];
  __shared__ float m32[ROWS];
  __shared__ float zrow[ROWS];
#define CST(d, r) smem[(d) * 36 + (r)]
#define XS(r, k)  smem[(r) * 258 + (k)]

  // conflict-free staging mapping (R18): bank = 4*(t&7) + ((t>>3)&3) + const
  const int dl3 = t & 7, rl2 = (t >> 3) & 3, dm3 = t >> 5;
  const float* __restrict__ Cb = C + ((size_t)b * NN + n0) * DK;
#pragma unroll
  for (int j = 0; j < 32; ++j) {
    const int d = dl3 + 8 * dm3 + 64 * (j & 3);
    const int r = rl2 + 4 * (j >> 2);
    CST(d, r) = Cb[r * 256 + d];
  }
  __syncthreads();

  // C row norms: STRICT SEQUENTIAL 256-chain (frozen), 32 rows in parallel
  if (t < ROWS) {
    float ss = 0.0f;
    for (int d = 0; d < DK; ++d) {
      float c = CST(d, t);
      ss = __fadd_rn(ss, __fmul_rn(c, c));
    }
    nrm32[t] = fmaxf(__fsqrt_rn(ss), 1e-8f);
  }
  __syncthreads();
#pragma unroll
  for (int j = 0; j < 32; ++j) {
    const int d = dl3 + 8 * dm3 + 64 * (j & 3);
    const int r = rl2 + 4 * (j >> 2);
    CST(d, r) = __fdiv_rn(CST(d, r), nrm32[r]);
  }
  __syncthreads();

  const float tt = fmaxf(temp[0], 0.1f);
  const float tp = __fadd_rn(tt, 1e-8f);

  // sims GEMM: thread = 2 cols x 16 rows (8 row-pairs), pk_fma, ascending-d
  const int rbase = (t >> 7) * 16;
  const int c0 = t & 127;
  const int c1 = c0 + 128;
  f32x2 acc0[8], acc1[8];
#pragma unroll
  for (int j = 0; j < 8; ++j) {
    acc0[j] = (f32x2)(0.0f, 0.0f);
    acc1[j] = (f32x2)(0.0f, 0.0f);
  }
  const float* __restrict__ Hnb = Hn + (size_t)b * DK * DV;
  for (int d0 = 0; d0 < DK; d0 += 4) {
#pragma unroll
    for (int dd = 0; dd < 4; ++dd) {
      const int d = d0 + dd;
      const float ha = Hnb[(size_t)d * DV + c0];
      const float hb = Hnb[(size_t)d * DV + c1];
      f32x2 hha; hha.x = ha; hha.y = ha;
      f32x2 hhb; hhb.x = hb; hhb.y = hb;
#pragma unroll
      for (int j4 = 0; j4 < 4; ++j4) {
        const float4 cq = *reinterpret_cast<const float4*>(&CST(d, rbase + 4 * j4));
        f32x2 lo; lo.x = cq.x; lo.y = cq.y;
        f32x2 hi; hi.x = cq.z; hi.y = cq.w;
        pkfma(acc0[2 * j4],     lo, hha);
        pkfma(acc0[2 * j4 + 1], hi, hha);
        pkfma(acc1[2 * j4],     lo, hhb);
        pkfma(acc1[2 * j4 + 1], hi, hhb);
      }
    }
  }
  __syncthreads();   // all csT reads done before xs overlay writes

  // x = fl32(sims/tp) (frozen CR div), into overlaid xs
#pragma unroll
  for (int j = 0; j < 8; ++j) {
    XS(rbase + 2 * j,     c0) = __fdiv_rn(acc0[j].x, tp);
    XS(rbase + 2 * j + 1, c0) = __fdiv_rn(acc0[j].y, tp);
    XS(rbase + 2 * j,     c1) = __fdiv_rn(acc1[j].x, tp);
    XS(rbase + 2 * j + 1, c1) = __fdiv_rn(acc1[j].y, tp);
  }
  __syncthreads();

  // row max (exact): 8 threads per row
  {
    const int r = t >> 3, j0 = t & 7;
    float m = XS(r, j0);
#pragma unroll
    for (int i = 1; i < 32; ++i) m = fmaxf(m, XS(r, j0 + 8 * i));
    m = fmaxf(m, __shfl_xor(m, 1, 64));
    m = fmaxf(m, __shfl_xor(m, 2, 64));
    m = fmaxf(m, __shfl_xor(m, 4, 64));
    if (j0 == 0) m32[r] = m;
  }
  __syncthreads();

  // e = CR exp(x - m) in place (frozen)
  for (int r = 0; r < ROWS; ++r)
    XS(r, t) = fexp_cr(__fsub_rn(XS(r, t), m32[r]));
  __syncthreads();

  // Z: STRICT SEQUENTIAL 256-chain per row (frozen)
  if (t < ROWS) {
    float zacc = 0.0f;
    for (int k = 0; k < DV; ++k) zacc = __fadd_rn(zacc, XS(t, k));
    zrow[t] = zacc;
  }
  __syncthreads();

  // selection + output: 2 rows interleaved; wave-max via DPP ladder (VALU),
  // ballot ties-LOW + clears byte-identical to R18.
  for (int p = 0; p < 4; ++p) {
    const int ra = w * 8 + 2 * p;
    const int rb = ra + 1;
    const float Za = zrow[ra];
    const float Zb = zrow[rb];
    unsigned int a0 = __float_as_uint(__fdiv_rn(XS(ra, l), Za));
    unsigned int a1 = __float_as_uint(__fdiv_rn(XS(ra, l + 64), Za));
    unsigned int a2 = __float_as_uint(__fdiv_rn(XS(ra, l + 128), Za));
    unsigned int a3 = __float_as_uint(__fdiv_rn(XS(ra, l + 192), Za));
    unsigned int b0 = __float_as_uint(__fdiv_rn(XS(rb, l), Zb));
    unsigned int b1 = __float_as_uint(__fdiv_rn(XS(rb, l + 64), Zb));
    unsigned int b2 = __float_as_uint(__fdiv_rn(XS(rb, l + 128), Zb));
    unsigned int b3 = __float_as_uint(__fdiv_rn(XS(rb, l + 192), Zb));

    float avalA[16], avalB[16];
    int idxA[16], idxB[16];
#pragma unroll
    for (int e = 0; e < 16; ++e) {
      unsigned int la = a0 > a1 ? a0 : a1;
      unsigned int l2a = a2 > a3 ? a2 : a3;
      la = la > l2a ? la : l2a;
      unsigned int lb = b0 > b1 ? b0 : b1;
      unsigned int l2b = b2 > b3 ? b2 : b3;
      lb = lb > l2b ? lb : l2b;
      la = wave_max_u32(la);
      lb = wave_max_u32(lb);
      unsigned long long ba0 = __ballot(a0 == la);
      unsigned long long ba1 = __ballot(a1 == la);
      unsigned long long ba2 = __ballot(a2 == la);
      unsigned long long ba3 = __ballot(a3 == la);
      unsigned long long bb0 = __ballot(b0 == lb);
      unsigned long long bb1 = __ballot(b1 == lb);
      unsigned long long bb2 = __ballot(b2 == lb);
      unsigned long long bb3 = __ballot(b3 == lb);
      int ida, idb;
      if (ba0)      ida = __ffsll(ba0) - 1;
      else if (ba1) ida = 64 + __ffsll(ba1) - 1;
      else if (ba2) ida = 128 + __ffsll(ba2) - 1;
      else          ida = 192 + __ffsll(ba3) - 1;
      if (bb0)      idb = __ffsll(bb0) - 1;
      else if (bb1) idb = 64 + __ffsll(bb1) - 1;
      else if (bb2) idb = 128 + __ffsll(bb2) - 1;
      else          idb = 192 + __ffsll(bb3) - 1;
      avalA[e] = __uint_as_float(la);
      avalB[e] = __uint_as_float(lb);
      idxA[e] = ida;
      idxB[e] = idb;
      if (l == (ida & 63)) {
        const int slot = ida >> 6;
        if (slot == 0) a0 = 0u;
        else if (slot == 1) a1 = 0u;
        else if (slot == 2) a2 = 0u;
        else a3 = 0u;
      }
      if (l == (idb & 63)) {
        const int slot = idb >> 6;
        if (slot == 0) b0 = 0u;
        else if (slot == 1) b1 = 0u;
        else if (slot == 2) b2 = 0u;
        else b3 = 0u;
      }
    }

    float Sa = avalA[0], Sb = avalB[0];
#pragma unroll
    for (int e = 1; e < 16; ++e) {
      Sa = __fadd_rn(Sa, avalA[e]);
      Sb = __fadd_rn(Sb, avalB[e]);
    }
    const float rSa = __frcp_rn(__fadd_rn(Sa, 1e-8f));
    const float rSb = __frcp_rn(__fadd_rn(Sb, 1e-8f));

    float oa0 = 0.f, oa1 = 0.f, oa2 = 0.f, oa3 = 0.f;
    float ob0 = 0.f, ob1 = 0.f, ob2 = 0.f, ob3 = 0.f;
    const float* __restrict__ HTb = HT + (size_t)b * DV * DK;
#pragma unroll
    for (int e = 0; e < 16; ++e) {
      const float wja = avalA[e] * rSa;
      const float wjb = avalB[e] * rSb;
      const float* __restrict__ hra = HTb + (size_t)idxA[e] * DK;
      const float* __restrict__ hrb = HTb + (size_t)idxB[e] * DK;
      oa0 = fmaf(wja, hra[l], oa0);
      ob0 = fmaf(wjb, hrb[l], ob0);
      oa1 = fmaf(wja, hra[l + 64], oa1);
      ob1 = fmaf(wjb, hrb[l + 64], ob1);
      oa2 = fmaf(wja, hra[l + 128], oa2);
      ob2 = fmaf(wjb, hrb[l + 128], ob2);
      oa3 = fmaf(wja, hra[l + 192], oa3);
      ob3 = fmaf(wjb, hrb[l + 192], ob3);
    }
    float* __restrict__ orowa = out + ((size_t)(b * NN + n0 + ra)) * DK;
    float* __restrict__ orowb = out + ((size_t)(b * NN + n0 + rb)) * DK;
    orowa[l] = oa0;
    orowa[l + 64] = oa1;
    orowa[l + 128] = oa2;
    orowa[l + 192] = oa3;
    orowb[l] = ob0;
    orowb[l + 64] = ob1;
    orowb[l + 128] = ob2;
    orowb[l + 192] = ob3;
  }
#undef CST
#undef XS
}

extern "C" void kernel_launch(void* const* d_in, const int* in_sizes, int n_in,
                              void* d_out, int out_size, void* d_ws, size_t ws_size,
                              hipStream_t stream) {
  const float* C = (const float*)d_in[0];
  const float* H = (const float*)d_in[1];
  const float* temp = (const float*)d_in[2];
  float* out = (float*)d_out;
  char* ws = (char*)d_ws;

  float* Hn = (float*)ws;                 // 8 MiB
  float* HT = (float*)(ws + 8388608);     // 8 MiB

  hipLaunchKernelGGL(k_hprep, dim3(NB, 8), dim3(256), 0, stream, H, Hn, HT);
  hipLaunchKernelGGL(k_main, dim3(NB * (NN / ROWS)), dim3(256), 0, stream,
                     C, Hn, HT, temp, out);
}